// Round 1
// baseline (194.310 us; speedup 1.0000x reference)
//
#include <hip/hip_runtime.h>

typedef _Float16 f16;
typedef _Float16 f16x2 __attribute__((ext_vector_type(2)));
typedef _Float16 f16x8 __attribute__((ext_vector_type(8)));
typedef float    f32x4 __attribute__((ext_vector_type(4)));

#define DIM 128

// silu(x) = x / (1 + e^-x); v_exp_f32 is 2^x so scale by log2(e). v_rcp_f32 ~1ulp.
__device__ __forceinline__ float silu_f(float x) {
    float e = __builtin_amdgcn_exp2f(x * -1.44269504088896341f);
    return x * __builtin_amdgcn_rcpf(1.0f + e);
}

// N-split structure: block = 256 threads = 4 waves, block-tile = 64 rows.
// Wave w owns output features n in [w*32, w*32+32) for BOTH layers; those weight
// fragments live in VGPRs (64 regs/lane). emb and x1 are exchanged through LDS:
//   embs: [g][kt][lane] A-frags (16 KB), x1s: XOR-swizzled f16 chunks (16 KB).
// Total LDS 32 KB; __launch_bounds__(256,3) -> 3 waves/SIMD (12 waves/CU).
__global__ __launch_bounds__(256, 3)
void ts_mlp_kernel(const float* __restrict__ t,
                   const float* __restrict__ W1, const float* __restrict__ b1,
                   const float* __restrict__ W2, const float* __restrict__ b2,
                   float* __restrict__ out, int B) {
    __shared__ f16x8 embs[4][4][64];   // [row-group g][kt][lane], mfma A-frag layout
    __shared__ f16x2 x1s[4][256][4];   // [g][m*16 + (c^m)][dword]; <=2-way banked

    const int tid  = threadIdx.x;
    const int wv   = tid >> 6;
    const int lane = tid & 63;
    const int q    = lane >> 4;   // quad index 0..3
    const int ln   = lane & 15;
    const int par  = lane & 1;

    // ---- prologue: this wave's W1/W2 slices -> registers, B-frag layout:
    // w?r[nl][kt] lane L holds W[n][k], n = wv*32 + nl*16 + (L&15), k = kt*32+(L>>4)*8+j
    f16x8 w1r[2][4], w2r[2][4];
#pragma unroll
    for (int nl = 0; nl < 2; ++nl) {
        const int n = wv * 32 + nl * 16 + ln;
#pragma unroll
        for (int kt = 0; kt < 4; ++kt) {
            const int k0 = kt * 32 + q * 8;
            const float4* s1 = (const float4*)(W1 + n * DIM + k0);
            float4 lo = s1[0], hi = s1[1];
            f16x8 fr;
            fr[0] = (f16)lo.x; fr[1] = (f16)lo.y; fr[2] = (f16)lo.z; fr[3] = (f16)lo.w;
            fr[4] = (f16)hi.x; fr[5] = (f16)hi.y; fr[6] = (f16)hi.z; fr[7] = (f16)hi.w;
            w1r[nl][kt] = fr;
            const float4* s2 = (const float4*)(W2 + n * DIM + k0);
            lo = s2[0]; hi = s2[1];
            fr[0] = (f16)lo.x; fr[1] = (f16)lo.y; fr[2] = (f16)lo.z; fr[3] = (f16)lo.w;
            fr[4] = (f16)hi.x; fr[5] = (f16)hi.y; fr[6] = (f16)hi.z; fr[7] = (f16)hi.w;
            w2r[nl][kt] = fr;
        }
    }
    float b1v[2], b2v[2];
#pragma unroll
    for (int nl = 0; nl < 2; ++nl) {
        b1v[nl] = b1[wv * 32 + nl * 16 + ln];
        b2v[nl] = b2[wv * 32 + nl * 16 + ln];
    }

    const int ntiles = B >> 6;
    int tile = blockIdx.x;
    // prefetch t one tile ahead (hides the HBM-miss latency at tile start)
    float tv_next = (tile < ntiles) ? t[tile * 64 + wv * 16 + ln] : 0.0f;

    for (; tile < ntiles; tile += gridDim.x) {
        const float tv = tv_next;
        const int nxt = tile + gridDim.x;
        if (nxt < ntiles) tv_next = t[nxt * 64 + wv * 16 + ln];

        // ---- emb for this wave's 16 rows (row-group g = wv), directly in A-frag
        // layout: row = ln, k = kt*32 + q*8 + j. v_sin/v_cos take REVOLUTIONS:
        // phase_d * t / 2pi = d*t/256.
        const float t256 = tv * 0.00390625f;
        const float o256 = (1.0f - tv) * 0.00390625f;
#pragma unroll
        for (int kt = 0; kt < 4; ++kt) {
            f16x8 fr;
#pragma unroll
            for (int j = 0; j < 8; ++j) {
                const float fd = (float)(kt * 32 + q * 8 + j);
                const float c  = __builtin_amdgcn_cosf(fd * t256);
                const float s  = __builtin_amdgcn_sinf(fd * o256);
                fr[j] = (f16)(tv * (c + s));
            }
            embs[wv][kt][lane] = fr;   // ds_write_b128, conflict-free
        }
        __syncthreads();   // emb ready (also guarantees prev-tile x1 reads done)

        // ---- layer 1: all 4 row-groups x this wave's 2 feature-tiles (32 MFMAs)
        f32x4 acc[4][2];
#pragma unroll
        for (int g = 0; g < 4; ++g)
#pragma unroll
            for (int nl = 0; nl < 2; ++nl) acc[g][nl] = (f32x4){0.f, 0.f, 0.f, 0.f};
#pragma unroll
        for (int g = 0; g < 4; ++g) {
#pragma unroll
            for (int kt = 0; kt < 4; ++kt) {
                const f16x8 a = embs[g][kt][lane];   // ds_read_b128, conflict-free
#pragma unroll
                for (int nl = 0; nl < 2; ++nl)
                    acc[g][nl] = __builtin_amdgcn_mfma_f32_16x16x32_f16(
                        a, w1r[nl][kt], acc[g][nl], 0, 0, 0);
            }
        }

        // ---- epilogue 1: bias + silu, pack col-pairs cross-lane, write x1 fp16.
        // C layout: value r in lane L is x1[row = g*16 + q*4 + r][col = wv*32 + nl*16 + ln]
        // chunk (m, c=col>>3) lives at physical m*16 + (c ^ m) within group g.
#pragma unroll
        for (int g = 0; g < 4; ++g) {
#pragma unroll
            for (int nl = 0; nl < 2; ++nl) {
                float v[4], pv[4];
#pragma unroll
                for (int r = 0; r < 4; ++r) v[r] = silu_f(acc[g][nl][r] + b1v[nl]);
#pragma unroll
                for (int r = 0; r < 4; ++r) pv[r] = __shfl_xor(v[r], 1, 64);
                const int col = wv * 32 + nl * 16 + (ln & 14);  // even column of pair
                const int cch = col >> 3;                       // 16B chunk index
                const int hw  = (col & 7) >> 1;                 // dword within chunk
#pragma unroll
                for (int p = 0; p < 2; ++p) {
                    const int r = par * 2 + p;     // even lanes rows r=0,1; odd r=2,3
                    const int m = q * 4 + r;
                    const float lo = par ? pv[r] : v[r];
                    const float hi = par ? v[r] : pv[r];
                    f16x2 h; h.x = (f16)lo; h.y = (f16)hi;
                    x1s[g][m * 16 + (cch ^ m)][hw] = h;
                }
            }
        }
        __syncthreads();   // x1 ready (also guarantees prev emb reads done before rewrite)

        // ---- layer 2: A-frags from swizzled x1, weights from registers (32 MFMAs)
        f32x4 acc2[4][2];
#pragma unroll
        for (int g = 0; g < 4; ++g)
#pragma unroll
            for (int nl = 0; nl < 2; ++nl) acc2[g][nl] = (f32x4){0.f, 0.f, 0.f, 0.f};
#pragma unroll
        for (int g = 0; g < 4; ++g) {
#pragma unroll
            for (int kt = 0; kt < 4; ++kt) {
                const f16x8 a2 = *(const f16x8*)&x1s[g][ln * 16 + ((kt * 4 + q) ^ ln)][0];
#pragma unroll
                for (int nl = 0; nl < 2; ++nl)
                    acc2[g][nl] = __builtin_amdgcn_mfma_f32_16x16x32_f16(
                        a2, w2r[nl][kt], acc2[g][nl], 0, 0, 0);
            }
        }

        // ---- epilogue 2: bias + silu, fp32 store (16-lane x 4B = 64B segments)
#pragma unroll
        for (int g = 0; g < 4; ++g) {
#pragma unroll
            for (int nl = 0; nl < 2; ++nl) {
#pragma unroll
                for (int r = 0; r < 4; ++r) {
                    const float o = silu_f(acc2[g][nl][r] + b2v[nl]);
                    out[(size_t)(tile * 64 + g * 16 + q * 4 + r) * DIM
                        + wv * 32 + nl * 16 + ln] = o;
                }
            }
        }
    }
}

extern "C" void kernel_launch(void* const* d_in, const int* in_sizes, int n_in,
                              void* d_out, int out_size, void* d_ws, size_t ws_size,
                              hipStream_t stream) {
    const float* t  = (const float*)d_in[0];
    const float* W1 = (const float*)d_in[1];
    const float* b1 = (const float*)d_in[2];
    const float* W2 = (const float*)d_in[3];
    const float* b2 = (const float*)d_in[4];
    float* out = (float*)d_out;
    const int B = in_sizes[0];
    const int ntiles = B >> 6;              // 64 rows per block-tile
    // 3 blocks/CU x 256 CUs = 768 co-resident blocks; 4096 tiles -> 5-6 tiles each
    int grid = ntiles < 768 ? ntiles : 768;
    ts_mlp_kernel<<<dim3(grid), dim3(256), 0, stream>>>(t, W1, b1, W2, b2, out, B);
}